// Round 15
// baseline (306.826 us; speedup 1.0000x reference)
//
#include <hip/hip_runtime.h>
#include <hip/hip_bf16.h>

#define D_MODEL 2048
#define SEQ     2048
#define BATCH   2
#define NH      16
#define HD      128
#define MROWS   (BATCH*SEQ)   // 4096

typedef __attribute__((ext_vector_type(8)))  short bf16x8;
typedef __attribute__((ext_vector_type(4)))  float f32x4;
typedef __attribute__((ext_vector_type(16))) float f32x16;
typedef __attribute__((ext_vector_type(4)))  unsigned int u32x4;

// async global->LDS, 16B per lane. LDS dest is wave-uniform base + lane*16 (implicit).
static __device__ __forceinline__ void lds16(const void* g, void* l) {
    __builtin_amdgcn_global_load_lds(
        (const __attribute__((address_space(1))) void*)g,
        (__attribute__((address_space(3))) void*)l,
        16, 0, 0);
}

static __device__ __forceinline__ unsigned int pk2(float a, float b) {
    const unsigned int lo = __bfloat16_as_ushort(__float2bfloat16(a));
    const unsigned int hh = __bfloat16_as_ushort(__float2bfloat16(b));
    return lo | (hh << 16);
}
static __device__ __forceinline__ unsigned short bfu(float a) {
    return __bfloat16_as_ushort(__float2bfloat16(a));
}

// ---------------- all f32->bf16 conversions in one launch ----------------
__global__ __launch_bounds__(256) void cvt_all(
    const float* __restrict__ q,  const float* __restrict__ k,  const float* __restrict__ v,
    const float* __restrict__ wq, const float* __restrict__ wk, const float* __restrict__ wv,
    const float* __restrict__ wo,
    unsigned short* __restrict__ qb, unsigned short* __restrict__ kb, unsigned short* __restrict__ vb,
    unsigned short* __restrict__ wqb, unsigned short* __restrict__ wkb,
    unsigned short* __restrict__ wvb, unsigned short* __restrict__ wob)
{
    const int b = blockIdx.x;
    const float* src; unsigned short* dst; int idx;
    if (b < 24576) {
        const int s = b >> 13;
        idx = (b & 8191)*256 + threadIdx.x;
        src = (s==0) ? q : (s==1) ? k : v;
        dst = (s==0) ? qb : (s==1) ? kb : vb;
    } else {
        const int bb = b - 24576;
        const int s = bb >> 12;
        idx = (bb & 4095)*256 + threadIdx.x;
        src = (s==0) ? wq : (s==1) ? wk : (s==2) ? wv : wo;
        dst = (s==0) ? wqb : (s==1) ? wkb : (s==2) ? wvb : wob;
    }
    const float4 a = ((const float4*)src)[idx];
    ushort4 o;
    o.x = bfu(a.x); o.y = bfu(a.y); o.z = bfu(a.z); o.w = bfu(a.w);
    ((ushort4*)dst)[idx] = o;
}

// sincos table: tab[s*256 + d] = cos, tab[s*256+128+d] = sin
__global__ __launch_bounds__(256) void rope_table(float* __restrict__ tab)
{
    const int i = blockIdx.x*256 + threadIdx.x;
    const int s = i >> 7, d = i & 127;
    const float invf = expf(-(float)d * (9.210340371976184f / 1024.0f));
    const float f = (float)s * invf;
    tab[(size_t)s*256 + d]       = cosf(f);
    tab[(size_t)s*256 + 128 + d] = sinf(f);
}

// ===========================================================================
// GEMM v2 shape (verified r10-r14): BM=128, BN=256, BK=64, 8 waves (2Mx4N),
// 3 LDS buffers, stage t+2 during t, counted vmcnt(6), 2 phases x 16 MFMA,
// T2 swizzle (slot ^ row&7, pre-swizzled global source). K-loop conflicts: 0.
// ===========================================================================
#define GV2_DECLS                                                             \
    const int tid  = threadIdx.x;                                             \
    const int lane = tid & 63;                                                \
    const int w    = tid >> 6;                                                \
    const int wm   = w >> 2;                                                  \
    const int wn   = w & 3;                                                   \
    const int l15  = lane & 15;                                               \
    const int l4   = lane >> 4;                                               \
    const int lrow = lane >> 3;                                               \
    const int lslot= (lane & 7) ^ lrow;                                       \
    const int sl0  = ((l4)     ^ (l15 & 7)) << 4;                             \
    const int sl1  = ((4 + l4) ^ (l15 & 7)) << 4;                             \
    const int rA0m = (wm*64 +  0 + l15)*128, rA1m = (wm*64 + 16 + l15)*128,   \
              rA2m = (wm*64 + 32 + l15)*128, rA3m = (wm*64 + 48 + l15)*128;   \
    const int rB0m = 16384 + (wn*64 +  0 + l15)*128,                          \
              rB1m = 16384 + (wn*64 + 16 + l15)*128,                          \
              rB2m = 16384 + (wn*64 + 32 + l15)*128,                          \
              rB3m = 16384 + (wn*64 + 48 + l15)*128;

#define SA(Q_, KT_, I_) lds16(Ag + (size_t)(arow0 + (I_)*64 + w*8 + lrow)*2048 \
                                  + (KT_)*64 + lslot*8,                        \
                              smem + (Q_)*49152 + ((I_)*64 + w*8)*128)
#define SB(Q_, KT_, J_) lds16(Wg + (size_t)(wrow0 + (J_)*64 + w*8 + lrow)*2048 \
                                  + (KT_)*64 + lslot*8,                        \
                              smem + (Q_)*49152 + 16384 + ((J_)*64 + w*8)*128)

#define MF(AF, BF, I_, J_) acc[I_][J_] = \
    __builtin_amdgcn_mfma_f32_16x16x32_bf16(AF, BF, acc[I_][J_], 0, 0, 0)

#define GV2_KLOOP                                                              \
    f32x4 acc[4][4] = {};                                                      \
    { SA(0,0,0); SA(0,0,1); SB(0,0,0); SB(0,0,1); SB(0,0,2); SB(0,0,3);        \
      SA(1,1,0); SA(1,1,1); SB(1,1,0); SB(1,1,1); SB(1,1,2); SB(1,1,3); }      \
    asm volatile("s_waitcnt vmcnt(6)" ::: "memory");                           \
    __builtin_amdgcn_s_barrier();                                              \
    int bi3 = 0, q2 = 2;                                                       \
    for (int t = 0; t < 32; ++t) {                                             \
        const char* cb = smem + bi3*49152;                                     \
        const bool st = (t + 2 < 32);                                          \
        bf16x8 a0 = *(const bf16x8*)(cb + rA0m + sl0);                         \
        bf16x8 a1 = *(const bf16x8*)(cb + rA1m + sl0);                         \
        bf16x8 a2 = *(const bf16x8*)(cb + rA2m + sl0);                         \
        bf16x8 a3 = *(const bf16x8*)(cb + rA3m + sl0);                         \
        bf16x8 b0 = *(const bf16x8*)(cb + rB0m + sl0);                         \
        bf16x8 b1 = *(const bf16x8*)(cb + rB1m + sl0);                         \
        bf16x8 b2 = *(const bf16x8*)(cb + rB2m + sl0);                         \
        bf16x8 b3 = *(const bf16x8*)(cb + rB3m + sl0);                         \
        if (st) { SA(q2, t+2, 0); SA(q2, t+2, 1); SB(q2, t+2, 0); SB(q2, t+2, 1); } \
        __builtin_amdgcn_s_barrier();                                          \
        __builtin_amdgcn_s_setprio(1);                                         \
        MF(a0,b0,0,0); MF(a1,b0,1,0); MF(a2,b0,2,0); MF(a3,b0,3,0);            \
        MF(a0,b1,0,1); MF(a1,b1,1,1); MF(a2,b1,2,1); MF(a3,b1,3,1);            \
        MF(a0,b2,0,2); MF(a1,b2,1,2); MF(a2,b2,2,2); MF(a3,b2,3,2);            \
        MF(a0,b3,0,3); MF(a1,b3,1,3); MF(a2,b3,2,3); MF(a3,b3,3,3);            \
        __builtin_amdgcn_s_setprio(0);                                         \
        __builtin_amdgcn_s_barrier();                                          \
        a0 = *(const bf16x8*)(cb + rA0m + sl1);                                \
        a1 = *(const bf16x8*)(cb + rA1m + sl1);                                \
        a2 = *(const bf16x8*)(cb + rA2m + sl1);                                \
        a3 = *(const bf16x8*)(cb + rA3m + sl1);                                \
        b0 = *(const bf16x8*)(cb + rB0m + sl1);                                \
        b1 = *(const bf16x8*)(cb + rB1m + sl1);                                \
        b2 = *(const bf16x8*)(cb + rB2m + sl1);                                \
        b3 = *(const bf16x8*)(cb + rB3m + sl1);                                \
        if (st) { SB(q2, t+2, 2); SB(q2, t+2, 3); }                            \
        if (st)            { asm volatile("s_waitcnt vmcnt(6)" ::: "memory"); }\
        else if (t+1 < 32) { asm volatile("s_waitcnt vmcnt(0)" ::: "memory"); }\
        __builtin_amdgcn_s_barrier();                                          \
        __builtin_amdgcn_s_setprio(1);                                         \
        MF(a0,b0,0,0); MF(a1,b0,1,0); MF(a2,b0,2,0); MF(a3,b0,3,0);            \
        MF(a0,b1,0,1); MF(a1,b1,1,1); MF(a2,b1,2,1); MF(a3,b1,3,1);            \
        MF(a0,b2,0,2); MF(a1,b2,1,2); MF(a2,b2,2,2); MF(a3,b2,3,2);            \
        MF(a0,b3,0,3); MF(a1,b3,1,3); MF(a2,b3,2,3); MF(a3,b3,3,3);            \
        __builtin_amdgcn_s_setprio(0);                                         \
        __builtin_amdgcn_s_barrier();                                          \
        bi3 = (bi3 == 2) ? 0 : bi3 + 1;                                        \
        q2  = (q2  == 2) ? 0 : q2  + 1;                                        \
    }

// ---------------- QKV GEMM v2h: v2 K-loop + HYBRID epilogue -----------------
// mat==2 (V): direct transposed ushort4 writes from acc (no LDS, no barrier).
// mat<2 (Q/K): r10-verified Ct staging + fused RoPE.
__global__ __launch_bounds__(512) void gemm_qkv_v2h(
    const __hip_bfloat16* __restrict__ Aq,
    const __hip_bfloat16* __restrict__ Ak,
    const __hip_bfloat16* __restrict__ Av,
    const __hip_bfloat16* __restrict__ Wq, const __hip_bfloat16* __restrict__ Wk,
    const __hip_bfloat16* __restrict__ Wv,
    const float* __restrict__ bq, const float* __restrict__ bk, const float* __restrict__ bv,
    const float* __restrict__ tab,
    __hip_bfloat16* __restrict__ Qp, __hip_bfloat16* __restrict__ Kp,
    __hip_bfloat16* __restrict__ Vt)
{
    __shared__ char smem[147456];

    const int xcd = blockIdx.x & 7;
    const int rr2 = blockIdx.x >> 3;    // 0..95
    const int bm  = xcd*4 + (rr2 & 3);  // 0..31
    const int bn  = rr2 >> 2;           // 0..23
    const int mat = bn >> 3;            // 0=Q 1=K 2=V
    const int hd2 = bn & 7;             // 256-col group (2 heads)
    const __hip_bfloat16* Ag = (mat==0) ? Aq : (mat==1) ? Ak : Av;
    const __hip_bfloat16* Wg = (mat==0) ? Wq : (mat==1) ? Wk : Wv;
    const float*          bi = (mat==0) ? bq : (mat==1) ? bk : bv;
    const int arow0 = bm*128;
    const int wrow0 = hd2*256;

    GV2_DECLS
    GV2_KLOOP

    const int grow0 = bm*128;
    const int bb    = grow0 >> 11;
    const int s0    = grow0 & (SEQ-1);

    if (mat == 2) {
        // ---- V: direct transposed write, 4 consecutive s per ushort4 ----
        unsigned short* vt = (unsigned short*)Vt;
        #pragma unroll
        for (int i = 0; i < 4; i++) {
            #pragma unroll
            for (int j = 0; j < 4; j++) {
                const int col  = hd2*256 + wn*64 + j*16 + l15;
                const int head = col >> 7;
                const int d    = col & 127;
                const float bvv = bi[col];
                const int s = s0 + wm*64 + i*16 + l4*4;
                ushort4 pkd;
                pkd.x = bfu(acc[i][j][0] + bvv);
                pkd.y = bfu(acc[i][j][1] + bvv);
                pkd.z = bfu(acc[i][j][2] + bvv);
                pkd.w = bfu(acc[i][j][3] + bvv);
                *(ushort4*)(vt + ((size_t)(bb*16 + head)*HD + d)*SEQ + s) = pkd;
            }
        }
    } else {
        // ---- Q/K: Ct staging + fused RoPE (r10-verified path) ----
        __syncthreads();                 // all waves done with staging LDS
        float* Ct = (float*)smem;        // [128][256] f32, col^(row&31) swizzle

        #pragma unroll
        for (int i = 0; i < 4; i++) {
            #pragma unroll
            for (int j = 0; j < 4; j++) {
                const int col = wn*64 + j*16 + l15;
                const float bvv = bi[hd2*256 + col];
                #pragma unroll
                for (int rr = 0; rr < 4; rr++) {
                    const int row = wm*64 + i*16 + l4*4 + rr;
                    Ct[row*256 + (col ^ (row & 31))] = acc[i][j][rr] + bvv;
                }
            }
        }
        __syncthreads();

        __hip_bfloat16* Out = (mat==0) ? Qp : Kp;
        #pragma unroll
        for (int p = 0; p < 16; p++) {
            const int rl = p*8 + (tid>>6);      // 0..127
            const int kx = rl & 31;
            const int c0 = (tid & 63)*4;        // 0..252
            const float* tc = tab + (size_t)(s0 + rl)*256;
            float o[4];
            #pragma unroll
            for (int i2 = 0; i2 < 4; i2++) {
                const int c  = c0 + i2;
                const int h2 = c >> 7;
                const int d  = c & 127;
                const float xx = Ct[rl*256 + (c ^ kx)];
                const int   pd = (d < 64) ? (2*d + 1) : (2*d - 128);
                const float xp = Ct[rl*256 + ((h2*128 + pd) ^ kx)];
                const float cs = tc[d], sn = tc[128 + d];
                o[i2] = (d < 64) ? (xx*cs - xp*sn) : (xx*cs + xp*sn);
            }
            ushort4 pkd;
            pkd.x = bfu(o[0]); pkd.y = bfu(o[1]); pkd.z = bfu(o[2]); pkd.w = bfu(o[3]);
            *(ushort4*)(Out + (size_t)(grow0 + rl)*D_MODEL + hd2*256 + c0) = pkd;
        }
    }
}

// ---------------- O-projection GEMM v2 (frozen, ~30us) ----------------------
__global__ __launch_bounds__(512) void gemm_out_v2(
    const __hip_bfloat16* __restrict__ Ag,
    const __hip_bfloat16* __restrict__ Wg,
    const float* __restrict__ bias,
    float* __restrict__ C)
{
    __shared__ char smem[147456];

    const int xcd = blockIdx.x & 7;
    const int r2  = blockIdx.x >> 3;
    const int bm  = xcd*4 + (r2 & 3);
    const int bn  = r2 >> 2;
    const int arow0 = bm*128;
    const int wrow0 = bn*256;

    GV2_DECLS
    GV2_KLOOP

    float bvv[4];
    #pragma unroll
    for (int j = 0; j < 4; j++)
        bvv[j] = bias[bn*256 + wn*64 + j*16 + l15];
    #pragma unroll
    for (int i = 0; i < 4; i++) {
        #pragma unroll
        for (int j = 0; j < 4; j++) {
            const int col = bn*256 + wn*64 + j*16 + l15;
            #pragma unroll
            for (int rr = 0; rr < 4; rr++) {
                const int row = bm*128 + wm*64 + i*16 + l4*4 + rr;
                C[(size_t)row*D_MODEL + col] = acc[i][j][rr] + bvv[j];
            }
        }
    }
}

// ---------------------------------------------------------------------------
// Flash attention (r12 exact, measured best ~78us): KV chunk 64, 4 waves,
// fixed-offset exp2 softmax, swizzled LDS K/V dbuf.
// ---------------------------------------------------------------------------
__global__ __launch_bounds__(256, 2) void flash_attn(
    const __hip_bfloat16* __restrict__ Qg,
    const __hip_bfloat16* __restrict__ Kg,
    const __hip_bfloat16* __restrict__ Vtg,
    __hip_bfloat16* __restrict__ ctx)
{
    __shared__ __hip_bfloat16 Ks[2][64*128];
    __shared__ __hip_bfloat16 Vs[2][128*64];

    const int tid  = threadIdx.x;
    const int w    = tid >> 6;
    const int lane = tid & 63;
    const int l31  = lane & 31;
    const int hi   = lane >> 5;
    const bool hib = (hi != 0);

    const int bid0 = blockIdx.x;                     // 512 blocks
    const int bid  = (bid0 & 7)*64 + (bid0 >> 3);    // XCD-aware swizzle
    const int bh   = bid >> 4;
    const int qt   = bid & 15;
    const int bi   = bh >> 4, h = bh & 15;
    const int q0   = qt * 128;

    const float SC2 = 0.12751745f;   // log2(e)/sqrt(128)
    const float MS  = 8.0f;          // fixed offset (log2 domain)

    bf16x8 aq[8];
    {
        const __hip_bfloat16* qp =
            Qg + (size_t)(bi*SEQ + q0 + w*32 + l31)*D_MODEL + h*HD + hi*8;
        #pragma unroll
        for (int ds = 0; ds < 8; ds++) aq[ds] = *(const bf16x8*)(qp + ds*16);
    }

#define STAGE(NB, KV) do {                                                              \
        _Pragma("unroll")                                                               \
        for (int i_ = 0; i_ < 4; i_++) {                                                \
            const int kr_ = w*16 + i_*4 + (lane>>4);                                    \
            lds16(Kg + (size_t)(bi*SEQ + (KV) + kr_)*D_MODEL + h*HD                     \
                      + (((lane&15) ^ (kr_&15))*8),                                     \
                  &Ks[NB][(w*16 + i_*4)*128]);                                          \
        }                                                                               \
        _Pragma("unroll")                                                               \
        for (int i_ = 0; i_ < 4; i_++) {                                                \
            const int vr_ = w*32 + i_*8 + (lane>>3);                                    \
            lds16(Vtg + ((size_t)bh*HD + vr_)*SEQ + (KV)                                \
                      + (((lane&7) ^ (lane>>3))*8),                                     \
                  &Vs[NB][(w*32 + i_*8)*64]);                                           \
        }                                                                               \
    } while (0)

    f32x16 o0 = {}, o1 = {}, o2 = {}, o3 = {};
    float l_run = 0.0f;

    STAGE(0, 0);

    for (int t = 0; t < SEQ/64; t++) {
        const int cb = t & 1;
        __syncthreads();
        if (t < SEQ/64 - 1) STAGE(cb^1, (t+1)*64);

        f32x16 p0 = {}, p1 = {};
        #pragma unroll
        for (int ds = 0; ds < 8; ds++) {
            const int sl = ((ds*2 + hi) ^ (lane&15)) * 8;
            const bf16x8 k0 = *(const bf16x8*)&Ks[cb][l31*128 + sl];
            const bf16x8 k1 = *(const bf16x8*)&Ks[cb][(32 + l31)*128 + sl];
            p0 = __builtin_amdgcn_mfma_f32_32x32x16_bf16(k0, aq[ds], p0, 0, 0, 0);
            p1 = __builtin_amdgcn_mfma_f32_32x32x16_bf16(k1, aq[ds], p1, 0, 0, 0);
        }

        #pragma unroll
        for (int r = 0; r < 16; r++) {
            p0[r] = __builtin_amdgcn_exp2f(__builtin_fmaf(p0[r], SC2, -MS));
            p1[r] = __builtin_amdgcn_exp2f(__builtin_fmaf(p1[r], SC2, -MS));
        }
        float rs = 0.0f;
        #pragma unroll
        for (int r = 0; r < 16; r++) rs += p0[r] + p1[r];
        rs += __shfl_xor(rs, 32);
        l_run += rs;

#define PV_STEP(PF, KS) do {                                                            \
            const unsigned int A0_ = pk2(PF[8*((KS)&1)+0], PF[8*((KS)&1)+1]);           \
            const unsigned int A1_ = pk2(PF[8*((KS)&1)+2], PF[8*((KS)&1)+3]);           \
            const unsigned int B0_ = pk2(PF[8*((KS)&1)+4], PF[8*((KS)&1)+5]);           \
            const unsigned int B1_ = pk2(PF[8*((KS)&1)+6], PF[8*((KS)&1)+7]);           \
            const unsigned int s0_ = hib ? A0_ : B0_;                                   \
            const unsigned int s1_ = hib ? A1_ : B1_;                                   \
            const unsigned int r0_ = (unsigned int)__shfl_xor((int)s0_, 32);            \
            const unsigned int r1_ = (unsigned int)__shfl_xor((int)s1_, 32);            \
            u32x4 au_;                                                                  \
            au_.x = hib ? r0_ : A0_;  au_.y = hib ? r1_ : A1_;                          \
            au_.z = hib ? B0_ : r0_;  au_.w = hib ? B1_ : r1_;                          \
            const bf16x8 pa_ = *(const bf16x8*)&au_;                                    \
            const int ko_ = (((KS)*2 + hi) ^ (lane&7)) * 8;                             \
            o0 = __builtin_amdgcn_mfma_f32_32x32x16_bf16(pa_,                           \
                     *(const bf16x8*)&Vs[cb][(  0 + l31)*64 + ko_], o0, 0, 0, 0);       \
            o1 = __builtin_amdgcn_mfma_f32_32x32x16_bf16(pa_,                           \
                     *(const bf16x8*)&Vs[cb][( 32 + l31)*64 + ko_], o1, 0, 0, 0);       \
            o2 = __builtin_amdgcn_mfma_f32_32x32x16_bf16(pa_,                           \
                     *(const bf16x8*)&Vs[cb][( 64 + l31)*64 + ko_], o2, 0, 0, 0);       \
            o3 = __builtin_amdgcn_mfma_f32_32x32x16_bf16(pa_,                           \
                     *(const bf16x8*)&Vs[cb][( 96 + l31)*64 + ko_], o3, 0, 0, 0);       \
        } while (0)

        PV_STEP(p0, 0); PV_STEP(p0, 1); PV_STEP(p1, 2); PV_STEP(p1, 3);
#undef PV_STEP
    }

    const float inv = 1.0f / l_run;
    float invr[16];
    #pragma unroll
    for (int r = 0; r < 16; r++)
        invr[r] = __shfl(inv, (r&3) + 8*(r>>2) + (hib ? 4 : 0));

    #pragma unroll
    for (int r = 0; r < 16; r++) {
        const int qr = q0 + w*32 + (r&3) + 8*(r>>2) + (hib ? 4 : 0);
        __hip_bfloat16* cp = ctx + (size_t)(bi*SEQ + qr)*D_MODEL + h*HD + l31;
        cp[0]  = __float2bfloat16(o0[r] * invr[r]);
        cp[32] = __float2bfloat16(o1[r] * invr[r]);
        cp[64] = __float2bfloat16(o2[r] * invr[r]);
        cp[96] = __float2bfloat16(o3[r] * invr[r]);
    }
#undef STAGE
}

extern "C" void kernel_launch(void* const* d_in, const int* in_sizes, int n_in,
                              void* d_out, int out_size, void* d_ws, size_t ws_size,
                              hipStream_t stream)
{
    const float* query = (const float*)d_in[0];
    const float* key   = (const float*)d_in[1];
    const float* value = (const float*)d_in[2];
    const float* Wq    = (const float*)d_in[3];
    const float* bq    = (const float*)d_in[4];
    const float* Wk    = (const float*)d_in[5];
    const float* bk    = (const float*)d_in[6];
    const float* Wv    = (const float*)d_in[7];
    const float* bv    = (const float*)d_in[8];
    const float* Wo    = (const float*)d_in[9];
    const float* bo    = (const float*)d_in[10];
    float* out = (float*)d_out;

    char* ws = (char*)d_ws;
    const size_t MB = 1024*1024;
    __hip_bfloat16* qb  = (__hip_bfloat16*)(ws);
    __hip_bfloat16* kbuf= (__hip_bfloat16*)(ws + 16*MB);
    __hip_bfloat16* vbuf= (__hip_bfloat16*)(ws + 32*MB);
    __hip_bfloat16* Qp  = (__hip_bfloat16*)(ws + 48*MB);
    __hip_bfloat16* Kp  = (__hip_bfloat16*)(ws + 64*MB);
    __hip_bfloat16* Vt  = (__hip_bfloat16*)(ws + 80*MB);
    __hip_bfloat16* ctx = (__hip_bfloat16*)(ws + 96*MB);
    __hip_bfloat16* Wqb = (__hip_bfloat16*)(ws + 112*MB);
    __hip_bfloat16* Wkb = (__hip_bfloat16*)(ws + 120*MB);
    __hip_bfloat16* Wvb = (__hip_bfloat16*)(ws + 128*MB);
    __hip_bfloat16* Wob = (__hip_bfloat16*)(ws + 136*MB);
    float*          tab = (float*)         (ws + 144*MB);

    cvt_all<<<40960, 256, 0, stream>>>(query, key, value, Wq, Wk, Wv, Wo,
        (unsigned short*)qb, (unsigned short*)kbuf, (unsigned short*)vbuf,
        (unsigned short*)Wqb, (unsigned short*)Wkb, (unsigned short*)Wvb,
        (unsigned short*)Wob);

    rope_table<<<SEQ*HD/256, 256, 0, stream>>>(tab);

    gemm_qkv_v2h<<<768, 512, 0, stream>>>(
        qb, kbuf, vbuf, Wqb, Wkb, Wvb, bq, bk, bv, tab, Qp, Kp, Vt);

    flash_attn<<<BATCH*NH*(SEQ/128), 256, 0, stream>>>(Qp, Kp, Vt, ctx);

    gemm_out_v2<<<256, 512, 0, stream>>>(ctx, Wob, bo, out);
}

// Round 17
// 301.573 us; speedup vs baseline: 1.0174x; 1.0174x over previous
//
#include <hip/hip_runtime.h>
#include <hip/hip_bf16.h>

#define D_MODEL 2048
#define SEQ     2048
#define BATCH   2
#define NH      16
#define HD      128
#define MROWS   (BATCH*SEQ)   // 4096

typedef __attribute__((ext_vector_type(8)))  short bf16x8;
typedef __attribute__((ext_vector_type(4)))  float f32x4;
typedef __attribute__((ext_vector_type(16))) float f32x16;
typedef __attribute__((ext_vector_type(4)))  unsigned int u32x4;

// async global->LDS, 16B per lane. LDS dest is wave-uniform base + lane*16 (implicit).
static __device__ __forceinline__ void lds16(const void* g, void* l) {
    __builtin_amdgcn_global_load_lds(
        (const __attribute__((address_space(1))) void*)g,
        (__attribute__((address_space(3))) void*)l,
        16, 0, 0);
}

static __device__ __forceinline__ unsigned int pk2(float a, float b) {
    const unsigned int lo = __bfloat16_as_ushort(__float2bfloat16(a));
    const unsigned int hh = __bfloat16_as_ushort(__float2bfloat16(b));
    return lo | (hh << 16);
}
static __device__ __forceinline__ unsigned short bfu(float a) {
    return __bfloat16_as_ushort(__float2bfloat16(a));
}
static __device__ __forceinline__ float b2f(unsigned int us16) {
    union { unsigned int u; float f; } cv; cv.u = us16 << 16; return cv.f;
}

// ---------------- all f32->bf16 conversions in one launch ----------------
__global__ __launch_bounds__(256) void cvt_all(
    const float* __restrict__ q,  const float* __restrict__ k,  const float* __restrict__ v,
    const float* __restrict__ wq, const float* __restrict__ wk, const float* __restrict__ wv,
    const float* __restrict__ wo,
    unsigned short* __restrict__ qb, unsigned short* __restrict__ kb, unsigned short* __restrict__ vb,
    unsigned short* __restrict__ wqb, unsigned short* __restrict__ wkb,
    unsigned short* __restrict__ wvb, unsigned short* __restrict__ wob)
{
    const int b = blockIdx.x;
    const float* src; unsigned short* dst; int idx;
    if (b < 24576) {
        const int s = b >> 13;
        idx = (b & 8191)*256 + threadIdx.x;
        src = (s==0) ? q : (s==1) ? k : v;
        dst = (s==0) ? qb : (s==1) ? kb : vb;
    } else {
        const int bb = b - 24576;
        const int s = bb >> 12;
        idx = (bb & 4095)*256 + threadIdx.x;
        src = (s==0) ? wq : (s==1) ? wk : (s==2) ? wv : wo;
        dst = (s==0) ? wqb : (s==1) ? wkb : (s==2) ? wvb : wob;
    }
    const float4 a = ((const float4*)src)[idx];
    ushort4 o;
    o.x = bfu(a.x); o.y = bfu(a.y); o.z = bfu(a.z); o.w = bfu(a.w);
    ((ushort4*)dst)[idx] = o;
}

// sincos table: tab[s*256 + d] = cos, tab[s*256+128+d] = sin
__global__ __launch_bounds__(256) void rope_table(float* __restrict__ tab)
{
    const int i = blockIdx.x*256 + threadIdx.x;
    const int s = i >> 7, d = i & 127;
    const float invf = expf(-(float)d * (9.210340371976184f / 1024.0f));
    const float f = (float)s * invf;
    tab[(size_t)s*256 + d]       = cosf(f);
    tab[(size_t)s*256 + 128 + d] = sinf(f);
}

// ===========================================================================
// GEMM v2 shape (verified r10-r14): BM=128, BN=256, BK=64, 8 waves (2Mx4N),
// 3 LDS buffers, stage t+2 during t, counted vmcnt(6), 2 phases x 16 MFMA,
// T2 swizzle (slot ^ row&7, pre-swizzled global source). K-loop conflicts: 0.
// ===========================================================================
#define GV2_DECLS                                                             \
    const int tid  = threadIdx.x;                                             \
    const int lane = tid & 63;                                                \
    const int w    = tid >> 6;                                                \
    const int wm   = w >> 2;                                                  \
    const int wn   = w & 3;                                                   \
    const int l15  = lane & 15;                                               \
    const int l4   = lane >> 4;                                               \
    const int lrow = lane >> 3;                                               \
    const int lslot= (lane & 7) ^ lrow;                                       \
    const int sl0  = ((l4)     ^ (l15 & 7)) << 4;                             \
    const int sl1  = ((4 + l4) ^ (l15 & 7)) << 4;                             \
    const int rA0m = (wm*64 +  0 + l15)*128, rA1m = (wm*64 + 16 + l15)*128,   \
              rA2m = (wm*64 + 32 + l15)*128, rA3m = (wm*64 + 48 + l15)*128;   \
    const int rB0m = 16384 + (wn*64 +  0 + l15)*128,                          \
              rB1m = 16384 + (wn*64 + 16 + l15)*128,                          \
              rB2m = 16384 + (wn*64 + 32 + l15)*128,                          \
              rB3m = 16384 + (wn*64 + 48 + l15)*128;

#define SA(Q_, KT_, I_) lds16(Ag + (size_t)(arow0 + (I_)*64 + w*8 + lrow)*2048 \
                                  + (KT_)*64 + lslot*8,                        \
                              smem + (Q_)*49152 + ((I_)*64 + w*8)*128)
#define SB(Q_, KT_, J_) lds16(Wg + (size_t)(wrow0 + (J_)*64 + w*8 + lrow)*2048 \
                                  + (KT_)*64 + lslot*8,                        \
                              smem + (Q_)*49152 + 16384 + ((J_)*64 + w*8)*128)

#define MF(AF, BF, I_, J_) acc[I_][J_] = \
    __builtin_amdgcn_mfma_f32_16x16x32_bf16(AF, BF, acc[I_][J_], 0, 0, 0)

#define GV2_KLOOP                                                              \
    f32x4 acc[4][4] = {};                                                      \
    { SA(0,0,0); SA(0,0,1); SB(0,0,0); SB(0,0,1); SB(0,0,2); SB(0,0,3);        \
      SA(1,1,0); SA(1,1,1); SB(1,1,0); SB(1,1,1); SB(1,1,2); SB(1,1,3); }      \
    asm volatile("s_waitcnt vmcnt(6)" ::: "memory");                           \
    __builtin_amdgcn_s_barrier();                                              \
    int bi3 = 0, q2 = 2;                                                       \
    for (int t = 0; t < 32; ++t) {                                             \
        const char* cb = smem + bi3*49152;                                     \
        const bool st = (t + 2 < 32);                                          \
        bf16x8 a0 = *(const bf16x8*)(cb + rA0m + sl0);                         \
        bf16x8 a1 = *(const bf16x8*)(cb + rA1m + sl0);                         \
        bf16x8 a2 = *(const bf16x8*)(cb + rA2m + sl0);                         \
        bf16x8 a3 = *(const bf16x8*)(cb + rA3m + sl0);                         \
        bf16x8 b0 = *(const bf16x8*)(cb + rB0m + sl0);                         \
        bf16x8 b1 = *(const bf16x8*)(cb + rB1m + sl0);                         \
        bf16x8 b2 = *(const bf16x8*)(cb + rB2m + sl0);                         \
        bf16x8 b3 = *(const bf16x8*)(cb + rB3m + sl0);                         \
        if (st) { SA(q2, t+2, 0); SA(q2, t+2, 1); SB(q2, t+2, 0); SB(q2, t+2, 1); } \
        __builtin_amdgcn_s_barrier();                                          \
        __builtin_amdgcn_s_setprio(1);                                         \
        MF(a0,b0,0,0); MF(a1,b0,1,0); MF(a2,b0,2,0); MF(a3,b0,3,0);            \
        MF(a0,b1,0,1); MF(a1,b1,1,1); MF(a2,b1,2,1); MF(a3,b1,3,1);            \
        MF(a0,b2,0,2); MF(a1,b2,1,2); MF(a2,b2,2,2); MF(a3,b2,3,2);            \
        MF(a0,b3,0,3); MF(a1,b3,1,3); MF(a2,b3,2,3); MF(a3,b3,3,3);            \
        __builtin_amdgcn_s_setprio(0);                                         \
        __builtin_amdgcn_s_barrier();                                          \
        a0 = *(const bf16x8*)(cb + rA0m + sl1);                                \
        a1 = *(const bf16x8*)(cb + rA1m + sl1);                                \
        a2 = *(const bf16x8*)(cb + rA2m + sl1);                                \
        a3 = *(const bf16x8*)(cb + rA3m + sl1);                                \
        b0 = *(const bf16x8*)(cb + rB0m + sl1);                                \
        b1 = *(const bf16x8*)(cb + rB1m + sl1);                                \
        b2 = *(const bf16x8*)(cb + rB2m + sl1);                                \
        b3 = *(const bf16x8*)(cb + rB3m + sl1);                                \
        if (st) { SB(q2, t+2, 2); SB(q2, t+2, 3); }                            \
        if (st)            { asm volatile("s_waitcnt vmcnt(6)" ::: "memory"); }\
        else if (t+1 < 32) { asm volatile("s_waitcnt vmcnt(0)" ::: "memory"); }\
        __builtin_amdgcn_s_barrier();                                          \
        __builtin_amdgcn_s_setprio(1);                                         \
        MF(a0,b0,0,0); MF(a1,b0,1,0); MF(a2,b0,2,0); MF(a3,b0,3,0);            \
        MF(a0,b1,0,1); MF(a1,b1,1,1); MF(a2,b1,2,1); MF(a3,b1,3,1);            \
        MF(a0,b2,0,2); MF(a1,b2,1,2); MF(a2,b2,2,2); MF(a3,b2,3,2);            \
        MF(a0,b3,0,3); MF(a1,b3,1,3); MF(a2,b3,2,3); MF(a3,b3,3,3);            \
        __builtin_amdgcn_s_setprio(0);                                         \
        __builtin_amdgcn_s_barrier();                                          \
        bi3 = (bi3 == 2) ? 0 : bi3 + 1;                                        \
        q2  = (q2  == 2) ? 0 : q2  + 1;                                        \
    }

// ---------------- QKV GEMM v2d (r14-verified: 114.7us, 0 conflicts) ---------
__global__ __launch_bounds__(512) void gemm_qkv_v2d(
    const __hip_bfloat16* __restrict__ Aq,
    const __hip_bfloat16* __restrict__ Ak,
    const __hip_bfloat16* __restrict__ Av,
    const __hip_bfloat16* __restrict__ Wq, const __hip_bfloat16* __restrict__ Wk,
    const __hip_bfloat16* __restrict__ Wv,
    const float* __restrict__ bq, const float* __restrict__ bk, const float* __restrict__ bv,
    __hip_bfloat16* __restrict__ Qp, __hip_bfloat16* __restrict__ Kp,
    __hip_bfloat16* __restrict__ Vp)
{
    __shared__ char smem[147456];

    const int xcd = blockIdx.x & 7;
    const int rr2 = blockIdx.x >> 3;    // 0..95
    const int bm  = xcd*4 + (rr2 & 3);  // 0..31
    const int bn  = rr2 >> 2;           // 0..23
    const int mat = bn >> 3;            // 0=Q 1=K 2=V
    const int hd2 = bn & 7;             // 256-col group
    const __hip_bfloat16* Ag = (mat==0) ? Aq : (mat==1) ? Ak : Av;
    const __hip_bfloat16* Wg = (mat==0) ? Wq : (mat==1) ? Wk : Wv;
    const float*          bi = (mat==0) ? bq : (mat==1) ? bk : bv;
    __hip_bfloat16*       Out= (mat==0) ? Qp : (mat==1) ? Kp : Vp;
    const int arow0 = bm*128;
    const int wrow0 = hd2*256;

    GV2_DECLS
    GV2_KLOOP

    float bvv[4];
    #pragma unroll
    for (int j = 0; j < 4; j++)
        bvv[j] = bi[hd2*256 + wn*64 + j*16 + l15];
    #pragma unroll
    for (int i = 0; i < 4; i++) {
        #pragma unroll
        for (int j = 0; j < 4; j++) {
            const int col = hd2*256 + wn*64 + j*16 + l15;
            #pragma unroll
            for (int rr = 0; rr < 4; rr++) {
                const int row = bm*128 + wm*64 + i*16 + l4*4 + rr;
                Out[(size_t)row*D_MODEL + col] = __float2bfloat16(acc[i][j][rr] + bvv[j]);
            }
        }
    }
}

// ---------------- rope_tv2b: vectorized RoPE + V transpose ------------------
// FIX vs r16: shuffle BOTH packed words, select at DESTINATION (the source's
// own fh selected the wrong word for dest lanes 8..15 / 24..31).
// blocks [0,16384): RoPE; [16384,18432): V transpose (r3-verified body).
__global__ __launch_bounds__(256) void rope_tv2(
    __hip_bfloat16* __restrict__ Qp, __hip_bfloat16* __restrict__ Kp,
    const unsigned short* __restrict__ Vp, unsigned short* __restrict__ Vt,
    const float* __restrict__ tab)
{
    __shared__ unsigned short tsh[64][66];
    const int blk = blockIdx.x;
    if (blk < 16384) {
        const int tid  = threadIdx.x;
        const int w    = tid >> 6, lane = tid & 63;
        const int lp   = lane & 31;          // lane within row
        const int rh   = lane >> 5;          // row of the pair
        const int rp   = blk*4 + w;          // row-pair 0..65535
        unsigned int rowid = rp*2;
        __hip_bfloat16* X = Qp;
        if (rowid >= (unsigned)(BATCH*SEQ*NH)) { X = Kp; rowid -= BATCH*SEQ*NH; }
        const int s = (rowid >> 4) & (SEQ-1);          // pair shares s (rowid even)
        unsigned short* rowp = (unsigned short*)X + (size_t)(rowid + rh)*HD + lp*4;
        const uint2 v = *(const uint2*)rowp;           // d = 4lp .. 4lp+3
        const unsigned int w0 = v.x, w1 = v.y;         // (a,b) , (c,d3)
        const unsigned int u_bd = (w0 >> 16) | (w1 & 0xffff0000u);   // (b, d3)
        const unsigned int u_ac = (w0 & 0xffffu) | (w1 << 16);       // (a, c)
        const bool fh = (lp < 16);                     // d < 64 half (DEST)
        const int L0 = (rh << 5) + 2*(lp & 15);
        const unsigned int s0bd = (unsigned int)__shfl((int)u_bd, L0);
        const unsigned int s1bd = (unsigned int)__shfl((int)u_bd, L0 + 1);
        const unsigned int s0ac = (unsigned int)__shfl((int)u_ac, L0);
        const unsigned int s1ac = (unsigned int)__shfl((int)u_ac, L0 + 1);
        const unsigned int s0 = fh ? s0bd : s0ac;
        const unsigned int s1 = fh ? s1bd : s1ac;
        const float* tc = tab + (size_t)s*256;
        const float4 cs = *(const float4*)(tc + lp*4);
        const float4 sn = *(const float4*)(tc + 128 + lp*4);
        const float sg = fh ? -1.0f : 1.0f;
        const float o0 = b2f(w0 & 0xffffu)*cs.x + sg*b2f(s0 & 0xffffu)*sn.x;
        const float o1 = b2f(w0 >> 16)    *cs.y + sg*b2f(s0 >> 16)    *sn.y;
        const float o2 = b2f(w1 & 0xffffu)*cs.z + sg*b2f(s1 & 0xffffu)*sn.z;
        const float o3 = b2f(w1 >> 16)    *cs.w + sg*b2f(s1 >> 16)    *sn.w;
        ushort4 pkd;
        pkd.x = bfu(o0); pkd.y = bfu(o1); pkd.z = bfu(o2); pkd.w = bfu(o3);
        *(ushort4*)rowp = pkd;
    } else {
        const int bid = blk - 16384;
        const int st = bid & 31;
        const int dt = (bid >> 5) & 1;
        const int bh = bid >> 6;
        const int b  = bh >> 4, h = bh & 15;
        const int tid = threadIdx.x;
        const int r = tid >> 5;
        const int c = tid & 31;
        #pragma unroll
        for (int i = 0; i < 8; i++) {
            const int row = i*8 + r;
            const unsigned int v = *(const unsigned int*)(
                Vp + (size_t)(b*SEQ + st*64 + row)*D_MODEL + h*HD + dt*64 + c*2);
            tsh[row][c*2]   = (unsigned short)(v & 0xffffu);
            tsh[row][c*2+1] = (unsigned short)(v >> 16);
        }
        __syncthreads();
        #pragma unroll
        for (int i = 0; i < 8; i++) {
            const int drow = i*8 + r;
            const unsigned int pk = (unsigned int)tsh[c*2][drow] | ((unsigned int)tsh[c*2+1][drow] << 16);
            *(unsigned int*)(Vt + ((size_t)bh*HD + dt*64 + drow)*SEQ + st*64 + c*2) = pk;
        }
    }
}

// ---------------- O-projection GEMM v2 (frozen, ~30us) ----------------------
__global__ __launch_bounds__(512) void gemm_out_v2(
    const __hip_bfloat16* __restrict__ Ag,
    const __hip_bfloat16* __restrict__ Wg,
    const float* __restrict__ bias,
    float* __restrict__ C)
{
    __shared__ char smem[147456];

    const int xcd = blockIdx.x & 7;
    const int r2  = blockIdx.x >> 3;
    const int bm  = xcd*4 + (r2 & 3);
    const int bn  = r2 >> 2;
    const int arow0 = bm*128;
    const int wrow0 = bn*256;

    GV2_DECLS
    GV2_KLOOP

    float bvv[4];
    #pragma unroll
    for (int j = 0; j < 4; j++)
        bvv[j] = bias[bn*256 + wn*64 + j*16 + l15];
    #pragma unroll
    for (int i = 0; i < 4; i++) {
        #pragma unroll
        for (int j = 0; j < 4; j++) {
            const int col = bn*256 + wn*64 + j*16 + l15;
            #pragma unroll
            for (int rr = 0; rr < 4; rr++) {
                const int row = bm*128 + wm*64 + i*16 + l4*4 + rr;
                C[(size_t)row*D_MODEL + col] = acc[i][j][rr] + bvv[j];
            }
        }
    }
}

// ---------------------------------------------------------------------------
// Flash attention (r12 exact, measured best ~78us): KV chunk 64, 4 waves,
// fixed-offset exp2 softmax, swizzled LDS K/V dbuf.
// ---------------------------------------------------------------------------
__global__ __launch_bounds__(256, 2) void flash_attn(
    const __hip_bfloat16* __restrict__ Qg,
    const __hip_bfloat16* __restrict__ Kg,
    const __hip_bfloat16* __restrict__ Vtg,
    __hip_bfloat16* __restrict__ ctx)
{
    __shared__ __hip_bfloat16 Ks[2][64*128];
    __shared__ __hip_bfloat16 Vs[2][128*64];

    const int tid  = threadIdx.x;
    const int w    = tid >> 6;
    const int lane = tid & 63;
    const int l31  = lane & 31;
    const int hi   = lane >> 5;
    const bool hib = (hi != 0);

    const int bid0 = blockIdx.x;                     // 512 blocks
    const int bid  = (bid0 & 7)*64 + (bid0 >> 3);    // XCD-aware swizzle
    const int bh   = bid >> 4;
    const int qt   = bid & 15;
    const int bi   = bh >> 4, h = bh & 15;
    const int q0   = qt * 128;

    const float SC2 = 0.12751745f;   // log2(e)/sqrt(128)
    const float MS  = 8.0f;          // fixed offset (log2 domain)

    bf16x8 aq[8];
    {
        const __hip_bfloat16* qp =
            Qg + (size_t)(bi*SEQ + q0 + w*32 + l31)*D_MODEL + h*HD + hi*8;
        #pragma unroll
        for (int ds = 0; ds < 8; ds++) aq[ds] = *(const bf16x8*)(qp + ds*16);
    }

#define STAGE(NB, KV) do {                                                              \
        _Pragma("unroll")                                                               \
        for (int i_ = 0; i_ < 4; i_++) {                                                \
            const int kr_ = w*16 + i_*4 + (lane>>4);                                    \
            lds16(Kg + (size_t)(bi*SEQ + (KV) + kr_)*D_MODEL + h*HD                     \
                      + (((lane&15) ^ (kr_&15))*8),                                     \
                  &Ks[NB][(w*16 + i_*4)*128]);                                          \
        }                                                                               \
        _Pragma("unroll")                                                               \
        for (int i_ = 0; i_ < 4; i_++) {                                                \
            const int vr_ = w*32 + i_*8 + (lane>>3);                                    \
            lds16(Vtg + ((size_t)bh*HD + vr_)*SEQ + (KV)                                \
                      + (((lane&7) ^ (lane>>3))*8),                                     \
                  &Vs[NB][(w*32 + i_*8)*64]);                                           \
        }                                                                               \
    } while (0)

    f32x16 o0 = {}, o1 = {}, o2 = {}, o3 = {};
    float l_run = 0.0f;

    STAGE(0, 0);

    for (int t = 0; t < SEQ/64; t++) {
        const int cb = t & 1;
        __syncthreads();
        if (t < SEQ/64 - 1) STAGE(cb^1, (t+1)*64);

        f32x16 p0 = {}, p1 = {};
        #pragma unroll
        for (int ds = 0; ds < 8; ds++) {
            const int sl = ((ds*2 + hi) ^ (lane&15)) * 8;
            const bf16x8 k0 = *(const bf16x8*)&Ks[cb][l31*128 + sl];
            const bf16x8 k1 = *(const bf16x8*)&Ks[cb][(32 + l31)*128 + sl];
            p0 = __builtin_amdgcn_mfma_f32_32x32x16_bf16(k0, aq[ds], p0, 0, 0, 0);
            p1 = __builtin_amdgcn_mfma_f32_32x32x16_bf16(k1, aq[ds], p1, 0, 0, 0);
        }

        #pragma unroll
        for (int r = 0; r < 16; r++) {
            p0[r] = __builtin_amdgcn_exp2f(__builtin_fmaf(p0[r], SC2, -MS));
            p1[r] = __builtin_amdgcn_exp2f(__builtin_fmaf(p1[r], SC2, -MS));
        }
        float rs = 0.0f;
        #pragma unroll
        for (int r = 0; r < 16; r++) rs += p0[r] + p1[r];
        rs += __shfl_xor(rs, 32);
        l_run += rs;

#define PV_STEP(PF, KS) do {                                                            \
            const unsigned int A0_ = pk2(PF[8*((KS)&1)+0], PF[8*((KS)&1)+1]);           \
            const unsigned int A1_ = pk2(PF[8*((KS)&1)+2], PF[8*((KS)&1)+3]);           \
            const unsigned int B0_ = pk2(PF[8*((KS)&1)+4], PF[8*((KS)&1)+5]);           \
            const unsigned int B1_ = pk2(PF[8*((KS)&1)+6], PF[8*((KS)&1)+7]);           \
            const unsigned int s0_ = hib ? A0_ : B0_;                                   \
            const unsigned int s1_ = hib ? A1_ : B1_;                                   \
            const unsigned int r0_ = (unsigned int)__shfl_xor((int)s0_, 32);            \
            const unsigned int r1_ = (unsigned int)__shfl_xor((int)s1_, 32);            \
            u32x4 au_;                                                                  \
            au_.x = hib ? r0_ : A0_;  au_.y = hib ? r1_ : A1_;                          \
            au_.z = hib ? B0_ : r0_;  au_.w = hib ? B1_ : r1_;                          \
            const bf16x8 pa_ = *(const bf16x8*)&au_;                                    \
            const int ko_ = (((KS)*2 + hi) ^ (lane&7)) * 8;                             \
            o0 = __builtin_amdgcn_mfma_f32_32x32x16_bf16(pa_,                           \
                     *(const bf16x8*)&Vs[cb][(  0 + l31)*64 + ko_], o0, 0, 0, 0);       \
            o1 = __builtin_amdgcn_mfma_f32_32x32x16_bf16(pa_,                           \
                     *(const bf16x8*)&Vs[cb][( 32 + l31)*64 + ko_], o1, 0, 0, 0);       \
            o2 = __builtin_amdgcn_mfma_f32_32x32x16_bf16(pa_,                           \
                     *(const bf16x8*)&Vs[cb][( 64 + l31)*64 + ko_], o2, 0, 0, 0);       \
            o3 = __builtin_amdgcn_mfma_f32_32x32x16_bf16(pa_,                           \
                     *(const bf16x8*)&Vs[cb][( 96 + l31)*64 + ko_], o3, 0, 0, 0);       \
        } while (0)

        PV_STEP(p0, 0); PV_STEP(p0, 1); PV_STEP(p1, 2); PV_STEP(p1, 3);
#undef PV_STEP
    }

    const float inv = 1.0f / l_run;
    float invr[16];
    #pragma unroll
    for (int r = 0; r < 16; r++)
        invr[r] = __shfl(inv, (r&3) + 8*(r>>2) + (hib ? 4 : 0));

    #pragma unroll
    for (int r = 0; r < 16; r++) {
        const int qr = q0 + w*32 + (r&3) + 8*(r>>2) + (hib ? 4 : 0);
        __hip_bfloat16* cp = ctx + (size_t)(bi*SEQ + qr)*D_MODEL + h*HD + l31;
        cp[0]  = __float2bfloat16(o0[r] * invr[r]);
        cp[32] = __float2bfloat16(o1[r] * invr[r]);
        cp[64] = __float2bfloat16(o2[r] * invr[r]);
        cp[96] = __float2bfloat16(o3[r] * invr[r]);
    }
#undef STAGE
}

extern "C" void kernel_launch(void* const* d_in, const int* in_sizes, int n_in,
                              void* d_out, int out_size, void* d_ws, size_t ws_size,
                              hipStream_t stream)
{
    const float* query = (const float*)d_in[0];
    const float* key   = (const float*)d_in[1];
    const float* value = (const float*)d_in[2];
    const float* Wq    = (const float*)d_in[3];
    const float* bq    = (const float*)d_in[4];
    const float* Wk    = (const float*)d_in[5];
    const float* bk    = (const float*)d_in[6];
    const float* Wv    = (const float*)d_in[7];
    const float* bv    = (const float*)d_in[8];
    const float* Wo    = (const float*)d_in[9];
    const float* bo    = (const float*)d_in[10];
    float* out = (float*)d_out;

    char* ws = (char*)d_ws;
    const size_t MB = 1024*1024;
    __hip_bfloat16* qb  = (__hip_bfloat16*)(ws);
    __hip_bfloat16* kbuf= (__hip_bfloat16*)(ws + 16*MB);
    __hip_bfloat16* vbuf= (__hip_bfloat16*)(ws + 32*MB);
    __hip_bfloat16* Qp  = (__hip_bfloat16*)(ws + 48*MB);
    __hip_bfloat16* Kp  = (__hip_bfloat16*)(ws + 64*MB);
    __hip_bfloat16* Vp  = (__hip_bfloat16*)(ws + 80*MB);
    __hip_bfloat16* Vt  = (__hip_bfloat16*)(ws + 96*MB);
    __hip_bfloat16* ctx = (__hip_bfloat16*)(ws + 112*MB);
    __hip_bfloat16* Wqb = (__hip_bfloat16*)(ws + 128*MB);
    __hip_bfloat16* Wkb = (__hip_bfloat16*)(ws + 136*MB);
    __hip_bfloat16* Wvb = (__hip_bfloat16*)(ws + 144*MB);
    __hip_bfloat16* Wob = (__hip_bfloat16*)(ws + 152*MB);
    float*          tab = (float*)         (ws + 160*MB);

    cvt_all<<<40960, 256, 0, stream>>>(query, key, value, Wq, Wk, Wv, Wo,
        (unsigned short*)qb, (unsigned short*)kbuf, (unsigned short*)vbuf,
        (unsigned short*)Wqb, (unsigned short*)Wkb, (unsigned short*)Wvb,
        (unsigned short*)Wob);

    rope_table<<<SEQ*HD/256, 256, 0, stream>>>(tab);

    gemm_qkv_v2d<<<768, 512, 0, stream>>>(
        qb, kbuf, vbuf, Wqb, Wkb, Wvb, bq, bk, bv, Qp, Kp, Vp);

    rope_tv2<<<18432, 256, 0, stream>>>(Qp, Kp, (const unsigned short*)Vp,
                                        (unsigned short*)Vt, tab);

    flash_attn<<<BATCH*NH*(SEQ/128), 256, 0, stream>>>(Qp, Kp, Vt, ctx);

    gemm_out_v2<<<256, 512, 0, stream>>>(ctx, Wob, bo, out);
}